// Round 7
// baseline (292.715 us; speedup 1.0000x reference)
//
#include <hip/hip_runtime.h>

#define BS 64
#define S  512
#define E  1024
#define H  16
#define HD 64
#define SCALE 0.125f   // 1/sqrt(64)
#define CATT 8         // attention chunks (64 rows each)

// workspace float offsets
#define W_QIN  1024
#define W_QKBF 66560      // bf16 qk (SCALE-folded): 64*16*1024 ushorts = 524288 float slots
#define W_NUM  1115136    // 8 partial chunks x BS*H*E f32
#define W_DEN  9503744    // 8 x BS*H
#define W_CTX  9511936    // BS*E

typedef __attribute__((ext_vector_type(8))) short short8;
typedef __attribute__((ext_vector_type(4))) float floatx4;

union S8u { uint2 u2[2]; short8 s; };

__device__ __forceinline__ unsigned short bf16c(float x) {
    unsigned int u = __float_as_uint(x);
    return (unsigned short)((u + 0x7fffu + ((u >> 16) & 1u)) >> 16);
}
__device__ __forceinline__ unsigned int pack_bf16(float a, float b) {
    return (unsigned int)bf16c(a) | ((unsigned int)bf16c(b) << 16);
}
__device__ __forceinline__ void fma4(float4& acc, float s, const float4& v) {
    acc.x += s * v.x; acc.y += s * v.y; acc.z += s * v.z; acc.w += s * v.w;
}
__device__ __forceinline__ float dot4(const float4& a, const float4& b) {
    return a.x * b.x + a.y * b.y + a.z * b.z + a.w * b.w;
}
__device__ __forceinline__ void bfly8(float* a) {
    #pragma unroll
    for (int off = 32; off > 0; off >>= 1) {
        #pragma unroll
        for (int i = 0; i < 8; i++) a[i] += __shfl_xor(a[i], off, 64);
    }
}

// ---- 1. prep: mask position + gathered q-input row ----
__global__ void k_prep(const float* __restrict__ model, const float* __restrict__ knowledge,
                       const int* __restrict__ ids, const int* __restrict__ mask_id_p,
                       const int* __restrict__ kid_p, int* __restrict__ mp,
                       float* __restrict__ qin) {
    int b = blockIdx.x, tid = threadIdx.x;
    __shared__ int best;
    if (tid == 0) best = S;
    __syncthreads();
    int mid = mask_id_p[0];
    for (int s = tid; s < S; s += 256)
        if (ids[b * S + s] == mid) atomicMin(&best, s);
    __syncthreads();
    int m = (best == S) ? 0 : best;
    if (tid == 0) mp[b] = m;
    bool isk = (ids[b * S + m] == kid_p[0]);
    const float* qrow = isk ? knowledge + (size_t)b * E : model + ((size_t)(b * S + m)) * E;
    ((float4*)(qin + (size_t)b * E))[tid] = ((const float4*)qrow)[tid];
}

// ---- 2. fused q + qk -> qkbf (bf16, SCALE folded). block per (h, 4 batches) ----
__global__ void k_qgen(const float* __restrict__ qin, const float* __restrict__ w_in,
                       const float* __restrict__ b_in, unsigned short* __restrict__ qkbf) {
    int h = blockIdx.x, b0 = blockIdx.y * 4, t = threadIdx.x;
    __shared__ float qin_l[4][1024];
    __shared__ float qred[4][64][4];
    __shared__ float qs_l[4][64];
    #pragma unroll
    for (int k = 0; k < 4; k++) {
        int idx4 = k * 256 + t;
        int bb = idx4 >> 8, col = (idx4 & 255) * 4;
        *(float4*)&qin_l[bb][col] = *(const float4*)(qin + (size_t)(b0 + bb) * E + col);
    }
    __syncthreads();
    {
        int d = t >> 2, part = t & 3;
        const float* wr = w_in + (size_t)(h * HD + d) * E + part * 256;
        float acc[4] = {0.f, 0.f, 0.f, 0.f};
        #pragma unroll 8
        for (int i = 0; i < 64; i++) {
            float4 wv = *(const float4*)(wr + i * 4);
            #pragma unroll
            for (int bb = 0; bb < 4; bb++)
                acc[bb] += dot4(wv, *(const float4*)&qin_l[bb][part * 256 + i * 4]);
        }
        #pragma unroll
        for (int bb = 0; bb < 4; bb++) qred[bb][d][part] = acc[bb];
    }
    __syncthreads();
    if (t < 64) {
        float bias = b_in[h * HD + t];
        #pragma unroll
        for (int bb = 0; bb < 4; bb++)
            qs_l[bb][t] = qred[bb][t][0] + qred[bb][t][1] + qred[bb][t][2] + qred[bb][t][3] + bias;
    }
    __syncthreads();
    {
        int e0 = t * 4;
        const float* wk = w_in + (size_t)(E + h * HD) * E + e0;
        float4 acc[4];
        #pragma unroll
        for (int bb = 0; bb < 4; bb++) acc[bb] = make_float4(0.f, 0.f, 0.f, 0.f);
        #pragma unroll 8
        for (int d = 0; d < HD; d++) {
            float4 wv = *(const float4*)(wk + (size_t)d * E);
            #pragma unroll
            for (int bb = 0; bb < 4; bb++) fma4(acc[bb], qs_l[bb][d], wv);
        }
        #pragma unroll
        for (int bb = 0; bb < 4; bb++) {
            uint2 pk;
            pk.x = pack_bf16(acc[bb].x * SCALE, acc[bb].y * SCALE);
            pk.y = pack_bf16(acc[bb].z * SCALE, acc[bb].w * SCALE);
            *(uint2*)&qkbf[((size_t)(b0 + bb) * H + h) * E + e0] = pk;
        }
    }
}

// ---- 3. fused attention via MFMA, dual-layout staging + register-prefetch pipeline ----
// grid (BS, CATT): b=blockIdx.x (chunks of same batch share XCD -> qkbf L2 reuse).
// 512 thr (8 waves); 4 passes x 16 rows. Thread loads 8 x float4 of single rows (vector),
// prefetches pass p+1 during pass p's GEMMs.
__global__ __launch_bounds__(512, 4) void k_attn(
    const float* __restrict__ model, const float* __restrict__ knowledge,
    const int* __restrict__ ids, const int* __restrict__ kid_p,
    const unsigned short* __restrict__ qkbf, float* __restrict__ num, float* __restrict__ den) {
    __shared__ __align__(16) unsigned char Ubuf[73984];   // Rbuf(33024)+RbufT(40960) | Tbuf(65792)
    unsigned short* Rbuf  = (unsigned short*)Ubuf;         // 16 rows x 1032 (row-major, GEMM1 A)
    unsigned short* RbufT = (unsigned short*)(Ubuf + 33024); // 1024 e x 20 (col-major, GEMM2 B)
    float* Tbuf = (float*)Ubuf;
    __shared__ unsigned short Pbuf[16 * 40];
    __shared__ float Sred[4][16][17];
    __shared__ unsigned long long kmask_s;

    int tid = threadIdx.x;
    int w = tid >> 6, l = tid & 63;
    int quad = l >> 4, lm = l & 15;
    int b = blockIdx.x, c = blockIdx.y;
    int s0 = c * 64;

    if (w == 0) {
        int id = ids[b * S + s0 + l];
        unsigned long long mk = __ballot(id == kid_p[0]);
        if (l == 0) kmask_s = mk;
    }
    floatx4 accn[8];
    #pragma unroll
    for (int i = 0; i < 8; i++) accn[i] = (floatx4)0.f;
    float accden = 0.f;
    const float* kb = knowledge + (size_t)b * E;
    const float* mb = model + (size_t)b * S * E;
    // GEMM1 B-fragments: pass-invariant, load ONCE (waves 0-3; K-slice w*256)
    short8 qfr[8];
    if (w < 4) {
        const unsigned short* qh = qkbf + ((size_t)b * H + lm) * E;
        #pragma unroll
        for (int t = 0; t < 8; t++)
            qfr[t] = *(const short8*)(const void*)(qh + (w * 8 + t) * 32 + quad * 8);
    }
    __syncthreads();
    unsigned long long kmask = kmask_s;

    int hi = tid >> 8;              // 0/1: row parity
    int col4 = (tid & 255) * 4;     // 4-float column group
    const float* base0 = mb + (size_t)(s0 + hi) * E + col4;
    const float* kbase = kb + col4;

    float4 pf[8];
    #pragma unroll
    for (int k = 0; k < 8; k++) {   // preload pass 0
        int s = k * 2 + hi;
        const float* rp = ((kmask >> s) & 1ull) ? kbase : base0 + (size_t)(k * 2) * E;
        pf[k] = *(const float4*)rp;
    }

    for (int pass = 0; pass < 4; pass++) {
        // ---- stage prefetched 16 rows into Rbuf + RbufT ----
        #pragma unroll
        for (int k = 0; k < 8; k++) {
            int row = k * 2 + hi;
            float4 v = pf[k];
            unsigned short h0 = bf16c(v.x), h1 = bf16c(v.y), h2 = bf16c(v.z), h3 = bf16c(v.w);
            uint2 pk;
            pk.x = (unsigned int)h0 | ((unsigned int)h1 << 16);
            pk.y = (unsigned int)h2 | ((unsigned int)h3 << 16);
            *(uint2*)&Rbuf[row * 1032 + col4] = pk;
            RbufT[(col4 + 0) * 20 + row] = h0;
            RbufT[(col4 + 1) * 20 + row] = h1;
            RbufT[(col4 + 2) * 20 + row] = h2;
            RbufT[(col4 + 3) * 20 + row] = h3;
        }
        __syncthreads();
        // ---- issue next pass's global loads (in flight during GEMMs) ----
        if (pass < 3) {
            int rb = (pass + 1) * 16;
            #pragma unroll
            for (int k = 0; k < 8; k++) {
                int s = rb + k * 2 + hi;
                const float* rp = ((kmask >> s) & 1ull) ? kbase : base0 + (size_t)(rb + k * 2) * E;
                pf[k] = *(const float4*)rp;
            }
        }
        // ---- GEMM1 (waves 0-3, K=256 slice each): scores 16 rows x 16 heads ----
        if (w < 4) {
            floatx4 acs = (floatx4)0.f;
            #pragma unroll
            for (int t = 0; t < 8; t++) {
                int kk = w * 8 + t;
                short8 a = *(const short8*)(const void*)&Rbuf[lm * 1032 + kk * 32 + quad * 8];
                acs = __builtin_amdgcn_mfma_f32_16x16x32_bf16(a, qfr[t], acs, 0, 0, 0);
            }
            Sred[w][quad * 4 + 0][lm] = acs[0];
            Sred[w][quad * 4 + 1][lm] = acs[1];
            Sred[w][quad * 4 + 2][lm] = acs[2];
            Sred[w][quad * 4 + 3][lm] = acs[3];
        }
        __syncthreads();
        // ---- combine + exp + P (wave 0) ----
        if (w == 0) {
            float ex[4];
            #pragma unroll
            for (int r = 0; r < 4; r++) {
                int row = quad * 4 + r;
                float s = Sred[0][row][lm] + Sred[1][row][lm] + Sred[2][row][lm] + Sred[3][row][lm];
                ex[r] = __expf(s);          // SCALE folded into qkbf
                accden += ex[r];
            }
            uint2 pw;
            pw.x = (unsigned int)bf16c(ex[0]) | ((unsigned int)bf16c(ex[1]) << 16);
            pw.y = (unsigned int)bf16c(ex[2]) | ((unsigned int)bf16c(ex[3]) << 16);
            *(uint2*)&Pbuf[lm * 40 + quad * 4] = pw;
        }
        __syncthreads();
        // ---- GEMM2 (all waves): num[h][e] += P(16h x 16r, K padded 32) @ R(16r x e) ----
        short8 afr = {};
        if (quad < 2) afr = *(const short8*)(const void*)&Pbuf[lm * 40 + quad * 8];
        #pragma unroll
        for (int i = 0; i < 8; i++) {
            int e = (w * 8 + i) * 16 + lm;
            S8u bb; bb.s = (short8){};
            if (quad < 2) {
                bb.u2[0] = *(const uint2*)&RbufT[e * 20 + quad * 8];
                bb.u2[1] = *(const uint2*)&RbufT[e * 20 + quad * 8 + 4];
            }
            accn[i] = __builtin_amdgcn_mfma_f32_16x16x32_bf16(afr, bb.s, accn[i], 0, 0, 0);
        }
        __syncthreads();
    }
    // ---- epilogue: transpose accn through LDS, store num coalesced ----
    #pragma unroll
    for (int i = 0; i < 8; i++) {
        int e = (w * 8 + i) * 16 + lm;
        Tbuf[(quad * 4 + 0) * 1028 + e] = accn[i][0];
        Tbuf[(quad * 4 + 1) * 1028 + e] = accn[i][1];
        Tbuf[(quad * 4 + 2) * 1028 + e] = accn[i][2];
        Tbuf[(quad * 4 + 3) * 1028 + e] = accn[i][3];
    }
    if (w == 0) {
        accden += __shfl_xor(accden, 16, 64);
        accden += __shfl_xor(accden, 32, 64);
        if (l < 16) den[(size_t)(c * BS + b) * H + l] = accden;
    }
    __syncthreads();
    size_t base = ((size_t)(c * BS + b) * H) * E;
    #pragma unroll
    for (int k = 0; k < 8; k++) {
        int idx4 = k * 512 + tid;
        int h = idx4 >> 8, e4 = (idx4 & 255) * 4;
        *(float4*)(num + base + (size_t)idx4 * 4) = *(const float4*)&Tbuf[h * 1028 + e4];
    }
}

// ---- 4. combine + ctx: block per (h, 4 batches) ----
__global__ void k_pc(const float* __restrict__ num, const float* __restrict__ den,
                     const float* __restrict__ w_in, const float* __restrict__ b_in,
                     float* __restrict__ ctx) {
    int h = blockIdx.x, b0 = blockIdx.y * 4, t = threadIdx.x;
    __shared__ float p_l[4][1024];
    __shared__ float cred[4][64][4];
    __shared__ float inv_l[4];
    #pragma unroll
    for (int k = 0; k < 4; k++) {
        int idx4 = k * 256 + t;
        int bb = idx4 >> 8, e4 = (idx4 & 255) * 4;
        float4 a = make_float4(0.f, 0.f, 0.f, 0.f);
        #pragma unroll
        for (int cc = 0; cc < CATT; cc++) {
            float4 v = *(const float4*)(num + (((size_t)(cc * BS + b0 + bb) * H + h) * E) + e4);
            a.x += v.x; a.y += v.y; a.z += v.z; a.w += v.w;
        }
        *(float4*)&p_l[bb][e4] = a;
    }
    if (t < 4) {
        float ds = 0.f;
        for (int cc = 0; cc < CATT; cc++) ds += den[(size_t)(cc * BS + b0 + t) * H + h];
        inv_l[t] = 1.0f / ds;
    }
    __syncthreads();
    {
        int jj = t >> 2, part = t & 3;
        const float* wr = w_in + (size_t)(2 * E + h * HD + jj) * E + part * 256;
        float acc[4] = {0.f, 0.f, 0.f, 0.f};
        #pragma unroll 8
        for (int i = 0; i < 64; i++) {
            float4 wv = *(const float4*)(wr + i * 4);
            #pragma unroll
            for (int bb = 0; bb < 4; bb++)
                acc[bb] += dot4(wv, *(const float4*)&p_l[bb][part * 256 + i * 4]);
        }
        #pragma unroll
        for (int bb = 0; bb < 4; bb++) cred[bb][jj][part] = acc[bb];
    }
    __syncthreads();
    if (t < 64) {
        float bias = b_in[2 * E + h * HD + t];
        #pragma unroll
        for (int bb = 0; bb < 4; bb++) {
            float s = cred[bb][t][0] + cred[bb][t][1] + cred[bb][t][2] + cred[bb][t][3];
            ctx[(size_t)(b0 + bb) * E + h * HD + t] = inv_l[bb] * s + bias;
        }
    }
}

// ---- 5. out = origin_q + strength * (ctx @ Wout^T + bout), gated ----
__global__ void k_out(const float* __restrict__ model, const float* __restrict__ w_out,
                      const float* __restrict__ b_out, const float* __restrict__ ctx,
                      const int* __restrict__ mp, const int* __restrict__ empty,
                      const float* __restrict__ strength_p, float* __restrict__ out) {
    int w = threadIdx.x >> 6, l = threadIdx.x & 63;
    int j = blockIdx.x * 4 + w;
    int b0 = blockIdx.y * 8;
    const float* wr = w_out + (size_t)j * E;
    float4 wv[4];
    #pragma unroll
    for (int r = 0; r < 4; r++) wv[r] = *(const float4*)(wr + r * 256 + l * 4);
    float acc[8];
    #pragma unroll
    for (int bb = 0; bb < 8; bb++) {
        const float* src = ctx + (size_t)(b0 + bb) * E;
        float a = 0.f;
        #pragma unroll
        for (int r = 0; r < 4; r++) a += dot4(wv[r], *(const float4*)(src + r * 256 + l * 4));
        acc[bb] = a;
    }
    bfly8(acc);
    if (l < 8) {
        float myacc = acc[0];
        #pragma unroll
        for (int bb = 1; bb < 8; bb++) myacc = (l == bb) ? acc[bb] : myacc;
        int b = b0 + l;
        int m = mp[b];
        float orig = model[((size_t)(b * S + m)) * E + j];
        float bias = b_out[j];
        float st = strength_p[0];
        out[(size_t)b * E + j] = empty[b] ? orig : orig + st * (myacc + bias);
    }
}

extern "C" void kernel_launch(void* const* d_in, const int* in_sizes, int n_in,
                              void* d_out, int out_size, void* d_ws, size_t ws_size,
                              hipStream_t stream) {
    const float* model     = (const float*)d_in[0];
    const float* knowledge = (const float*)d_in[1];
    const float* w_in      = (const float*)d_in[2];
    const float* b_in      = (const float*)d_in[3];
    const float* w_out     = (const float*)d_in[4];
    const float* b_out     = (const float*)d_in[5];
    const float* strength  = (const float*)d_in[6];
    const int*   ids       = (const int*)d_in[7];
    const int*   empty     = (const int*)d_in[8];
    const int*   know_id   = (const int*)d_in[9];
    const int*   mask_id   = (const int*)d_in[10];
    float* out = (float*)d_out;

    float* ws  = (float*)d_ws;
    int*   mp  = (int*)d_ws;
    float* qin = ws + W_QIN;
    unsigned short* qkbf = (unsigned short*)(ws + W_QKBF);
    float* num = ws + W_NUM;
    float* den = ws + W_DEN;
    float* ctx = ws + W_CTX;

    k_prep<<<BS, 256, 0, stream>>>(model, knowledge, ids, mask_id, know_id, mp, qin);
    k_qgen<<<dim3(H, 16), 256, 0, stream>>>(qin, w_in, b_in, qkbf);
    k_attn<<<dim3(BS, CATT), 512, 0, stream>>>(model, knowledge, ids, know_id, qkbf, num, den);
    k_pc<<<dim3(H, 16), 256, 0, stream>>>(num, den, w_in, b_in, ctx);
    k_out<<<dim3(256, 8), 256, 0, stream>>>(model, w_out, b_out, ctx, mp, empty, strength, out);
}

// Round 8
// 290.031 us; speedup vs baseline: 1.0093x; 1.0093x over previous
//
#include <hip/hip_runtime.h>

#define BS 64
#define S  512
#define E  1024
#define H  16
#define HD 64
#define SCALE 0.125f   // 1/sqrt(64)
#define CATT 8         // attention chunks (64 rows each)

// workspace float offsets
#define W_QIN  1024
#define W_QKBF 66560      // bf16 qk (SCALE-folded): 64*16*1024 ushorts = 524288 float slots
#define W_NUM  1115136    // 8 partial chunks x BS*H*E f32
#define W_DEN  9503744    // 8 x BS*H
#define W_CTX  9511936    // BS*E

typedef __attribute__((ext_vector_type(8))) short short8;
typedef __attribute__((ext_vector_type(4))) float floatx4;

union S8u { uint2 u2[2]; short8 s; };

__device__ __forceinline__ unsigned short bf16c(float x) {
    unsigned int u = __float_as_uint(x);
    return (unsigned short)((u + 0x7fffu + ((u >> 16) & 1u)) >> 16);
}
__device__ __forceinline__ unsigned int pack_bf16(float a, float b) {
    return (unsigned int)bf16c(a) | ((unsigned int)bf16c(b) << 16);
}
__device__ __forceinline__ void fma4(float4& acc, float s, const float4& v) {
    acc.x += s * v.x; acc.y += s * v.y; acc.z += s * v.z; acc.w += s * v.w;
}
__device__ __forceinline__ float dot4(const float4& a, const float4& b) {
    return a.x * b.x + a.y * b.y + a.z * b.z + a.w * b.w;
}
__device__ __forceinline__ void bfly8(float* a) {
    #pragma unroll
    for (int off = 32; off > 0; off >>= 1) {
        #pragma unroll
        for (int i = 0; i < 8; i++) a[i] += __shfl_xor(a[i], off, 64);
    }
}

// ---- 1. prep: mask position + gathered q-input row ----
__global__ void k_prep(const float* __restrict__ model, const float* __restrict__ knowledge,
                       const int* __restrict__ ids, const int* __restrict__ mask_id_p,
                       const int* __restrict__ kid_p, int* __restrict__ mp,
                       float* __restrict__ qin) {
    int b = blockIdx.x, tid = threadIdx.x;
    __shared__ int best;
    if (tid == 0) best = S;
    __syncthreads();
    int mid = mask_id_p[0];
    for (int s = tid; s < S; s += 256)
        if (ids[b * S + s] == mid) atomicMin(&best, s);
    __syncthreads();
    int m = (best == S) ? 0 : best;
    if (tid == 0) mp[b] = m;
    bool isk = (ids[b * S + m] == kid_p[0]);
    const float* qrow = isk ? knowledge + (size_t)b * E : model + ((size_t)(b * S + m)) * E;
    ((float4*)(qin + (size_t)b * E))[tid] = ((const float4*)qrow)[tid];
}

// ---- 2. fused q + qk -> qkbf (bf16, SCALE folded). block per (h, 4 batches) ----
__global__ void k_qgen(const float* __restrict__ qin, const float* __restrict__ w_in,
                       const float* __restrict__ b_in, unsigned short* __restrict__ qkbf) {
    int h = blockIdx.x, b0 = blockIdx.y * 4, t = threadIdx.x;
    __shared__ float qin_l[4][1024];
    __shared__ float qred[4][64][4];
    __shared__ float qs_l[4][64];
    #pragma unroll
    for (int k = 0; k < 4; k++) {
        int idx4 = k * 256 + t;
        int bb = idx4 >> 8, col = (idx4 & 255) * 4;
        *(float4*)&qin_l[bb][col] = *(const float4*)(qin + (size_t)(b0 + bb) * E + col);
    }
    __syncthreads();
    {
        int d = t >> 2, part = t & 3;
        const float* wr = w_in + (size_t)(h * HD + d) * E + part * 256;
        float acc[4] = {0.f, 0.f, 0.f, 0.f};
        #pragma unroll 8
        for (int i = 0; i < 64; i++) {
            float4 wv = *(const float4*)(wr + i * 4);
            #pragma unroll
            for (int bb = 0; bb < 4; bb++)
                acc[bb] += dot4(wv, *(const float4*)&qin_l[bb][part * 256 + i * 4]);
        }
        #pragma unroll
        for (int bb = 0; bb < 4; bb++) qred[bb][d][part] = acc[bb];
    }
    __syncthreads();
    if (t < 64) {
        float bias = b_in[h * HD + t];
        #pragma unroll
        for (int bb = 0; bb < 4; bb++)
            qs_l[bb][t] = qred[bb][t][0] + qred[bb][t][1] + qred[bb][t][2] + qred[bb][t][3] + bias;
    }
    __syncthreads();
    {
        int e0 = t * 4;
        const float* wk = w_in + (size_t)(E + h * HD) * E + e0;
        float4 acc[4];
        #pragma unroll
        for (int bb = 0; bb < 4; bb++) acc[bb] = make_float4(0.f, 0.f, 0.f, 0.f);
        #pragma unroll 8
        for (int d = 0; d < HD; d++) {
            float4 wv = *(const float4*)(wk + (size_t)d * E);
            #pragma unroll
            for (int bb = 0; bb < 4; bb++) fma4(acc[bb], qs_l[bb][d], wv);
        }
        #pragma unroll
        for (int bb = 0; bb < 4; bb++) {
            uint2 pk;
            pk.x = pack_bf16(acc[bb].x * SCALE, acc[bb].y * SCALE);
            pk.y = pack_bf16(acc[bb].z * SCALE, acc[bb].w * SCALE);
            *(uint2*)&qkbf[((size_t)(b0 + bb) * H + h) * E + e0] = pk;
        }
    }
}

// ---- 3. fused attention via MFMA. grid (CATT, BS); 512 thr; 4 passes x 16 rows.
// v3: vector float4 staging + next-pass register prefetch, register P-fragment
// (exp computed per-wave from Sred, no Pbuf), 3 barriers/pass.
__global__ __launch_bounds__(512, 4) void k_attn(
    const float* __restrict__ model, const float* __restrict__ knowledge,
    const int* __restrict__ ids, const int* __restrict__ kid_p,
    const unsigned short* __restrict__ qkbf, float* __restrict__ num, float* __restrict__ den) {
    __shared__ __align__(16) unsigned char Ubuf[73984];   // Rbuf(33024)+RbufT(40960) | Tbuf(65792)
    unsigned short* Rbuf  = (unsigned short*)Ubuf;           // 16 rows x 1032 (GEMM1 A)
    unsigned short* RbufT = (unsigned short*)(Ubuf + 33024); // 1024 e x 20 (GEMM2 B)
    float* Tbuf = (float*)Ubuf;
    __shared__ float Sred[4][16][17];
    __shared__ unsigned long long kmask_s;

    int tid = threadIdx.x;
    int w = tid >> 6, l = tid & 63;
    int quad = l >> 4, lm = l & 15;
    int c = blockIdx.x, b = blockIdx.y;
    int s0 = c * 64;

    if (w == 0) {
        int id = ids[b * S + s0 + l];
        unsigned long long mk = __ballot(id == kid_p[0]);
        if (l == 0) kmask_s = mk;
    }
    floatx4 accn[8];
    #pragma unroll
    for (int i = 0; i < 8; i++) accn[i] = (floatx4)0.f;
    float accden = 0.f;
    const float* kb = knowledge + (size_t)b * E;
    const float* mb = model + (size_t)b * S * E;
    const unsigned short* qh = qkbf + ((size_t)b * H + lm) * E;
    __syncthreads();
    unsigned long long kmask = kmask_s;

    int hi = tid >> 8;              // 0/1: row parity
    int col4 = (tid & 255) * 4;     // 4-float column group
    const float* base0 = mb + (size_t)(s0 + hi) * E + col4;
    const float* kbase = kb + col4;

    float4 pf[8];
    #pragma unroll
    for (int k = 0; k < 8; k++) {   // preload pass 0
        int s = k * 2 + hi;
        const float* rp = ((kmask >> s) & 1ull) ? kbase : base0 + (size_t)(k * 2) * E;
        pf[k] = *(const float4*)rp;
    }

    for (int pass = 0; pass < 4; pass++) {
        // ---- stage prefetched 16 rows into Rbuf + RbufT ----
        #pragma unroll
        for (int k = 0; k < 8; k++) {
            int row = k * 2 + hi;
            float4 v = pf[k];
            unsigned short h0 = bf16c(v.x), h1 = bf16c(v.y), h2 = bf16c(v.z), h3 = bf16c(v.w);
            uint2 pk;
            pk.x = (unsigned int)h0 | ((unsigned int)h1 << 16);
            pk.y = (unsigned int)h2 | ((unsigned int)h3 << 16);
            *(uint2*)&Rbuf[row * 1032 + col4] = pk;
            RbufT[(col4 + 0) * 20 + row] = h0;
            RbufT[(col4 + 1) * 20 + row] = h1;
            RbufT[(col4 + 2) * 20 + row] = h2;
            RbufT[(col4 + 3) * 20 + row] = h3;
        }
        __syncthreads();
        // ---- issue next pass's global loads (fly during GEMMs) ----
        if (pass < 3) {
            int rb = (pass + 1) * 16;
            #pragma unroll
            for (int k = 0; k < 8; k++) {
                int s = rb + k * 2 + hi;
                const float* rp = ((kmask >> s) & 1ull) ? kbase : base0 + (size_t)(rb + k * 2) * E;
                pf[k] = *(const float4*)rp;
            }
        }
        // ---- GEMM1 (waves 0-3, K=256 slice each): scores 16 rows x 16 heads ----
        if (w < 4) {
            floatx4 acs = (floatx4)0.f;
            #pragma unroll
            for (int t = 0; t < 8; t++) {
                int kk = w * 8 + t;
                short8 a  = *(const short8*)(const void*)&Rbuf[lm * 1032 + kk * 32 + quad * 8];
                short8 bf = *(const short8*)(const void*)(qh + kk * 32 + quad * 8);
                acs = __builtin_amdgcn_mfma_f32_16x16x32_bf16(a, bf, acs, 0, 0, 0);
            }
            Sred[w][quad * 4 + 0][lm] = acs[0];
            Sred[w][quad * 4 + 1][lm] = acs[1];
            Sred[w][quad * 4 + 2][lm] = acs[2];
            Sred[w][quad * 4 + 3][lm] = acs[3];
        }
        __syncthreads();
        // ---- P fragment in registers (all waves; A[m=head=lm][k=row=quad*8+j]) ----
        S8u afr; afr.s = (short8){};
        if (quad < 2) {
            float ex[8];
            #pragma unroll
            for (int j = 0; j < 8; j++) {
                int row = quad * 8 + j;
                float sc = Sred[0][row][lm] + Sred[1][row][lm] + Sred[2][row][lm] + Sred[3][row][lm];
                ex[j] = __expf(sc);          // SCALE folded into qkbf
            }
            accden += ex[0] + ex[1] + ex[2] + ex[3] + ex[4] + ex[5] + ex[6] + ex[7];
            afr.u2[0].x = pack_bf16(ex[0], ex[1]);
            afr.u2[0].y = pack_bf16(ex[2], ex[3]);
            afr.u2[1].x = pack_bf16(ex[4], ex[5]);
            afr.u2[1].y = pack_bf16(ex[6], ex[7]);
        }
        // ---- GEMM2 (all waves): num[h][e] += P(16h x 16r, K padded 32) @ R(16r x e) ----
        #pragma unroll
        for (int i = 0; i < 8; i++) {
            int e = (w * 8 + i) * 16 + lm;
            S8u bb; bb.s = (short8){};
            if (quad < 2) {
                bb.u2[0] = *(const uint2*)&RbufT[e * 20 + quad * 8];
                bb.u2[1] = *(const uint2*)&RbufT[e * 20 + quad * 8 + 4];
            }
            accn[i] = __builtin_amdgcn_mfma_f32_16x16x32_bf16(afr.s, bb.s, accn[i], 0, 0, 0);
        }
        __syncthreads();
    }
    // ---- epilogue: transpose accn through LDS, store num coalesced ----
    #pragma unroll
    for (int i = 0; i < 8; i++) {
        int e = (w * 8 + i) * 16 + lm;
        Tbuf[(quad * 4 + 0) * 1028 + e] = accn[i][0];
        Tbuf[(quad * 4 + 1) * 1028 + e] = accn[i][1];
        Tbuf[(quad * 4 + 2) * 1028 + e] = accn[i][2];
        Tbuf[(quad * 4 + 3) * 1028 + e] = accn[i][3];
    }
    if (w == 0) {
        accden += __shfl_xor(accden, 16, 64);   // combine quad0+quad1
        if (l < 16) den[(size_t)(c * BS + b) * H + l] = accden;
    }
    __syncthreads();
    size_t base = ((size_t)(c * BS + b) * H) * E;
    #pragma unroll
    for (int k = 0; k < 8; k++) {
        int idx4 = k * 512 + tid;
        int h = idx4 >> 8, e4 = (idx4 & 255) * 4;
        *(float4*)(num + base + (size_t)idx4 * 4) = *(const float4*)&Tbuf[h * 1028 + e4];
    }
}

// ---- 4. combine + ctx: block per (h, 4 batches) ----
__global__ void k_pc(const float* __restrict__ num, const float* __restrict__ den,
                     const float* __restrict__ w_in, const float* __restrict__ b_in,
                     float* __restrict__ ctx) {
    int h = blockIdx.x, b0 = blockIdx.y * 4, t = threadIdx.x;
    __shared__ float p_l[4][1024];
    __shared__ float cred[4][64][4];
    __shared__ float inv_l[4];
    #pragma unroll
    for (int k = 0; k < 4; k++) {
        int idx4 = k * 256 + t;
        int bb = idx4 >> 8, e4 = (idx4 & 255) * 4;
        float4 a = make_float4(0.f, 0.f, 0.f, 0.f);
        #pragma unroll
        for (int cc = 0; cc < CATT; cc++) {
            float4 v = *(const float4*)(num + (((size_t)(cc * BS + b0 + bb) * H + h) * E) + e4);
            a.x += v.x; a.y += v.y; a.z += v.z; a.w += v.w;
        }
        *(float4*)&p_l[bb][e4] = a;
    }
    if (t < 4) {
        float ds = 0.f;
        for (int cc = 0; cc < CATT; cc++) ds += den[(size_t)(cc * BS + b0 + t) * H + h];
        inv_l[t] = 1.0f / ds;
    }
    __syncthreads();
    {
        int jj = t >> 2, part = t & 3;
        const float* wr = w_in + (size_t)(2 * E + h * HD + jj) * E + part * 256;
        float acc[4] = {0.f, 0.f, 0.f, 0.f};
        #pragma unroll 8
        for (int i = 0; i < 64; i++) {
            float4 wv = *(const float4*)(wr + i * 4);
            #pragma unroll
            for (int bb = 0; bb < 4; bb++)
                acc[bb] += dot4(wv, *(const float4*)&p_l[bb][part * 256 + i * 4]);
        }
        #pragma unroll
        for (int bb = 0; bb < 4; bb++) cred[bb][jj][part] = acc[bb];
    }
    __syncthreads();
    if (t < 64) {
        float bias = b_in[2 * E + h * HD + t];
        #pragma unroll
        for (int bb = 0; bb < 4; bb++) {
            float s = cred[bb][t][0] + cred[bb][t][1] + cred[bb][t][2] + cred[bb][t][3];
            ctx[(size_t)(b0 + bb) * E + h * HD + t] = inv_l[bb] * s + bias;
        }
    }
}

// ---- 5. out = origin_q + strength * (ctx @ Wout^T + bout), gated ----
__global__ void k_out(const float* __restrict__ model, const float* __restrict__ w_out,
                      const float* __restrict__ b_out, const float* __restrict__ ctx,
                      const int* __restrict__ mp, const int* __restrict__ empty,
                      const float* __restrict__ strength_p, float* __restrict__ out) {
    int w = threadIdx.x >> 6, l = threadIdx.x & 63;
    int j = blockIdx.x * 4 + w;
    int b0 = blockIdx.y * 8;
    const float* wr = w_out + (size_t)j * E;
    float4 wv[4];
    #pragma unroll
    for (int r = 0; r < 4; r++) wv[r] = *(const float4*)(wr + r * 256 + l * 4);
    float acc[8];
    #pragma unroll
    for (int bb = 0; bb < 8; bb++) {
        const float* src = ctx + (size_t)(b0 + bb) * E;
        float a = 0.f;
        #pragma unroll
        for (int r = 0; r < 4; r++) a += dot4(wv[r], *(const float4*)(src + r * 256 + l * 4));
        acc[bb] = a;
    }
    bfly8(acc);
    if (l < 8) {
        float myacc = acc[0];
        #pragma unroll
        for (int bb = 1; bb < 8; bb++) myacc = (l == bb) ? acc[bb] : myacc;
        int b = b0 + l;
        int m = mp[b];
        float orig = model[((size_t)(b * S + m)) * E + j];
        float bias = b_out[j];
        float st = strength_p[0];
        out[(size_t)b * E + j] = empty[b] ? orig : orig + st * (myacc + bias);
    }
}

extern "C" void kernel_launch(void* const* d_in, const int* in_sizes, int n_in,
                              void* d_out, int out_size, void* d_ws, size_t ws_size,
                              hipStream_t stream) {
    const float* model     = (const float*)d_in[0];
    const float* knowledge = (const float*)d_in[1];
    const float* w_in      = (const float*)d_in[2];
    const float* b_in      = (const float*)d_in[3];
    const float* w_out     = (const float*)d_in[4];
    const float* b_out     = (const float*)d_in[5];
    const float* strength  = (const float*)d_in[6];
    const int*   ids       = (const int*)d_in[7];
    const int*   empty     = (const int*)d_in[8];
    const int*   know_id   = (const int*)d_in[9];
    const int*   mask_id   = (const int*)d_in[10];
    float* out = (float*)d_out;

    float* ws  = (float*)d_ws;
    int*   mp  = (int*)d_ws;
    float* qin = ws + W_QIN;
    unsigned short* qkbf = (unsigned short*)(ws + W_QKBF);
    float* num = ws + W_NUM;
    float* den = ws + W_DEN;
    float* ctx = ws + W_CTX;

    k_prep<<<BS, 256, 0, stream>>>(model, knowledge, ids, mask_id, know_id, mp, qin);
    k_qgen<<<dim3(H, 16), 256, 0, stream>>>(qin, w_in, b_in, qkbf);
    k_attn<<<dim3(CATT, BS), 512, 0, stream>>>(model, knowledge, ids, know_id, qkbf, num, den);
    k_pc<<<dim3(H, 16), 256, 0, stream>>>(num, den, w_in, b_in, ctx);
    k_out<<<dim3(256, 8), 256, 0, stream>>>(model, w_out, b_out, ctx, mp, empty, strength, out);
}

// Round 9
// 279.185 us; speedup vs baseline: 1.0485x; 1.0388x over previous
//
#include <hip/hip_runtime.h>

#define BS 64
#define S  512
#define E  1024
#define H  16
#define HD 64
#define SCALE 0.125f   // 1/sqrt(64)
#define CATT 8         // attention chunks (64 rows each)

// workspace float offsets
#define W_QIN  1024
#define W_QKBF 66560      // bf16 qk (SCALE-folded): 64*16*1024 ushorts = 524288 float slots
#define W_NUM  1115136    // 8 partial chunks x BS*H*E bf16 (16 MB)
#define W_DEN  9503744    // 8 x BS*H f32
#define W_CTX  9511936    // BS*E f32

typedef __attribute__((ext_vector_type(8))) short short8;
typedef __attribute__((ext_vector_type(4))) float floatx4;

union S8u { uint2 u2[2]; short8 s; };

__device__ __forceinline__ unsigned short bf16c(float x) {
    unsigned int u = __float_as_uint(x);
    return (unsigned short)((u + 0x7fffu + ((u >> 16) & 1u)) >> 16);
}
__device__ __forceinline__ unsigned int pack_bf16(float a, float b) {
    return (unsigned int)bf16c(a) | ((unsigned int)bf16c(b) << 16);
}
__device__ __forceinline__ void fma4(float4& acc, float s, const float4& v) {
    acc.x += s * v.x; acc.y += s * v.y; acc.z += s * v.z; acc.w += s * v.w;
}
__device__ __forceinline__ float dot4(const float4& a, const float4& b) {
    return a.x * b.x + a.y * b.y + a.z * b.z + a.w * b.w;
}
__device__ __forceinline__ void bfly8(float* a) {
    #pragma unroll
    for (int off = 32; off > 0; off >>= 1) {
        #pragma unroll
        for (int i = 0; i < 8; i++) a[i] += __shfl_xor(a[i], off, 64);
    }
}

// ---- 1. prep: mask position + gathered q-input row ----
__global__ void k_prep(const float* __restrict__ model, const float* __restrict__ knowledge,
                       const int* __restrict__ ids, const int* __restrict__ mask_id_p,
                       const int* __restrict__ kid_p, int* __restrict__ mp,
                       float* __restrict__ qin) {
    int b = blockIdx.x, tid = threadIdx.x;
    __shared__ int best;
    if (tid == 0) best = S;
    __syncthreads();
    int mid = mask_id_p[0];
    for (int s = tid; s < S; s += 256)
        if (ids[b * S + s] == mid) atomicMin(&best, s);
    __syncthreads();
    int m = (best == S) ? 0 : best;
    if (tid == 0) mp[b] = m;
    bool isk = (ids[b * S + m] == kid_p[0]);
    const float* qrow = isk ? knowledge + (size_t)b * E : model + ((size_t)(b * S + m)) * E;
    ((float4*)(qin + (size_t)b * E))[tid] = ((const float4*)qrow)[tid];
}

// ---- 2. fused q + qk -> qkbf (bf16, SCALE folded). block per (h, 4 batches) ----
__global__ void k_qgen(const float* __restrict__ qin, const float* __restrict__ w_in,
                       const float* __restrict__ b_in, unsigned short* __restrict__ qkbf) {
    int h = blockIdx.x, b0 = blockIdx.y * 4, t = threadIdx.x;
    __shared__ float qin_l[4][1024];
    __shared__ float qred[4][64][4];
    __shared__ float qs_l[4][64];
    #pragma unroll
    for (int k = 0; k < 4; k++) {
        int idx4 = k * 256 + t;
        int bb = idx4 >> 8, col = (idx4 & 255) * 4;
        *(float4*)&qin_l[bb][col] = *(const float4*)(qin + (size_t)(b0 + bb) * E + col);
    }
    __syncthreads();
    {
        int d = t >> 2, part = t & 3;
        const float* wr = w_in + (size_t)(h * HD + d) * E + part * 256;
        float acc[4] = {0.f, 0.f, 0.f, 0.f};
        #pragma unroll 8
        for (int i = 0; i < 64; i++) {
            float4 wv = *(const float4*)(wr + i * 4);
            #pragma unroll
            for (int bb = 0; bb < 4; bb++)
                acc[bb] += dot4(wv, *(const float4*)&qin_l[bb][part * 256 + i * 4]);
        }
        #pragma unroll
        for (int bb = 0; bb < 4; bb++) qred[bb][d][part] = acc[bb];
    }
    __syncthreads();
    if (t < 64) {
        float bias = b_in[h * HD + t];
        #pragma unroll
        for (int bb = 0; bb < 4; bb++)
            qs_l[bb][t] = qred[bb][t][0] + qred[bb][t][1] + qred[bb][t][2] + qred[bb][t][3] + bias;
    }
    __syncthreads();
    {
        int e0 = t * 4;
        const float* wk = w_in + (size_t)(E + h * HD) * E + e0;
        float4 acc[4];
        #pragma unroll
        for (int bb = 0; bb < 4; bb++) acc[bb] = make_float4(0.f, 0.f, 0.f, 0.f);
        #pragma unroll 8
        for (int d = 0; d < HD; d++) {
            float4 wv = *(const float4*)(wk + (size_t)d * E);
            #pragma unroll
            for (int bb = 0; bb < 4; bb++) fma4(acc[bb], qs_l[bb][d], wv);
        }
        #pragma unroll
        for (int bb = 0; bb < 4; bb++) {
            uint2 pk;
            pk.x = pack_bf16(acc[bb].x * SCALE, acc[bb].y * SCALE);
            pk.y = pack_bf16(acc[bb].z * SCALE, acc[bb].w * SCALE);
            *(uint2*)&qkbf[((size_t)(b0 + bb) * H + h) * E + e0] = pk;
        }
    }
}

// ---- 3. fused attention via MFMA, dual-layout staging (R6 structure, bf16 num epilogue) ----
// block per (chunk c, batch b); 512 thr (8 waves); 4 passes x 16 rows.
__global__ __launch_bounds__(512, 4) void k_attn(
    const float* __restrict__ model, const float* __restrict__ knowledge,
    const int* __restrict__ ids, const int* __restrict__ kid_p,
    const unsigned short* __restrict__ qkbf, unsigned short* __restrict__ num,
    float* __restrict__ den) {
    __shared__ __align__(16) unsigned char Ubuf[73984];   // Rbuf(33024)+RbufT(40960) | TbufH(32768)
    unsigned short* Rbuf  = (unsigned short*)Ubuf;           // 16 rows x 1032 (GEMM1 A)
    unsigned short* RbufT = (unsigned short*)(Ubuf + 33024); // 1024 e x 20 (GEMM2 B)
    unsigned short* TbufH = (unsigned short*)Ubuf;           // epilogue: [h][e] stride 1024, bf16
    __shared__ unsigned short Pbuf[16 * 40];
    __shared__ float Sred[4][16][17];
    __shared__ unsigned long long kmask_s;

    int tid = threadIdx.x;
    int w = tid >> 6, l = tid & 63;
    int quad = l >> 4, lm = l & 15;
    int c = blockIdx.x, b = blockIdx.y;
    int s0 = c * 64;

    if (w == 0) {
        int id = ids[b * S + s0 + l];
        unsigned long long mk = __ballot(id == kid_p[0]);
        if (l == 0) kmask_s = mk;
    }
    floatx4 accn[8];
    #pragma unroll
    for (int i = 0; i < 8; i++) accn[i] = (floatx4)0.f;
    float accden = 0.f;
    const float* kb = knowledge + (size_t)b * E;
    const float* mb = model + (size_t)b * S * E;
    const unsigned short* qh = qkbf + ((size_t)b * H + lm) * E;
    __syncthreads();
    unsigned long long kmask = kmask_s;

    for (int pass = 0; pass < 4; pass++) {
        int rb = pass * 16;
        // ---- stage 16 rows into Rbuf (row-major) AND RbufT (transposed), coalesced 4B loads ----
        #pragma unroll
        for (int g = 0; g < 4; g++) {
            int r0 = g * 4;
            const float* rp0 = ((kmask >> (rb + r0 + 0)) & 1ull) ? kb : mb + (size_t)(s0 + rb + r0 + 0) * E;
            const float* rp1 = ((kmask >> (rb + r0 + 1)) & 1ull) ? kb : mb + (size_t)(s0 + rb + r0 + 1) * E;
            const float* rp2 = ((kmask >> (rb + r0 + 2)) & 1ull) ? kb : mb + (size_t)(s0 + rb + r0 + 2) * E;
            const float* rp3 = ((kmask >> (rb + r0 + 3)) & 1ull) ? kb : mb + (size_t)(s0 + rb + r0 + 3) * E;
            #pragma unroll
            for (int cc = 0; cc < 2; cc++) {
                int col = cc * 512 + tid;
                unsigned short h0 = bf16c(rp0[col]);
                unsigned short h1 = bf16c(rp1[col]);
                unsigned short h2 = bf16c(rp2[col]);
                unsigned short h3 = bf16c(rp3[col]);
                Rbuf[(r0 + 0) * 1032 + col] = h0;
                Rbuf[(r0 + 1) * 1032 + col] = h1;
                Rbuf[(r0 + 2) * 1032 + col] = h2;
                Rbuf[(r0 + 3) * 1032 + col] = h3;
                uint2 pk;
                pk.x = (unsigned int)h0 | ((unsigned int)h1 << 16);
                pk.y = (unsigned int)h2 | ((unsigned int)h3 << 16);
                *(uint2*)&RbufT[col * 20 + r0] = pk;
            }
        }
        __syncthreads();
        // ---- GEMM1 (waves 0-3, K=256 slice each): scores 16 rows x 16 heads ----
        if (w < 4) {
            floatx4 acs = (floatx4)0.f;
            #pragma unroll
            for (int t = 0; t < 8; t++) {
                int kk = w * 8 + t;
                short8 a  = *(const short8*)(const void*)&Rbuf[lm * 1032 + kk * 32 + quad * 8];
                short8 bf = *(const short8*)(const void*)(qh + kk * 32 + quad * 8);
                acs = __builtin_amdgcn_mfma_f32_16x16x32_bf16(a, bf, acs, 0, 0, 0);
            }
            Sred[w][quad * 4 + 0][lm] = acs[0];
            Sred[w][quad * 4 + 1][lm] = acs[1];
            Sred[w][quad * 4 + 2][lm] = acs[2];
            Sred[w][quad * 4 + 3][lm] = acs[3];
        }
        __syncthreads();
        // ---- combine + exp + P (wave 0) ----
        if (w == 0) {
            float ex[4];
            #pragma unroll
            for (int r = 0; r < 4; r++) {
                int row = quad * 4 + r;
                float s = Sred[0][row][lm] + Sred[1][row][lm] + Sred[2][row][lm] + Sred[3][row][lm];
                ex[r] = __expf(s);          // SCALE folded into qkbf
                accden += ex[r];
            }
            uint2 pw;
            pw.x = (unsigned int)bf16c(ex[0]) | ((unsigned int)bf16c(ex[1]) << 16);
            pw.y = (unsigned int)bf16c(ex[2]) | ((unsigned int)bf16c(ex[3]) << 16);
            *(uint2*)&Pbuf[lm * 40 + quad * 4] = pw;
        }
        __syncthreads();
        // ---- GEMM2 (all waves): num[h][e] += P(16h x 16r, K padded 32) @ R(16r x e) ----
        short8 afr = {};
        if (quad < 2) afr = *(const short8*)(const void*)&Pbuf[lm * 40 + quad * 8];
        #pragma unroll
        for (int i = 0; i < 8; i++) {
            int e = (w * 8 + i) * 16 + lm;
            S8u bb; bb.s = (short8){};
            if (quad < 2) {
                bb.u2[0] = *(const uint2*)&RbufT[e * 20 + quad * 8];
                bb.u2[1] = *(const uint2*)&RbufT[e * 20 + quad * 8 + 4];
            }
            accn[i] = __builtin_amdgcn_mfma_f32_16x16x32_bf16(afr, bb.s, accn[i], 0, 0, 0);
        }
        __syncthreads();
    }
    // ---- epilogue: pack accn to bf16, transpose through LDS, store coalesced ----
    #pragma unroll
    for (int i = 0; i < 8; i++) {
        int e = (w * 8 + i) * 16 + lm;
        TbufH[(quad * 4 + 0) * 1024 + e] = bf16c(accn[i][0]);
        TbufH[(quad * 4 + 1) * 1024 + e] = bf16c(accn[i][1]);
        TbufH[(quad * 4 + 2) * 1024 + e] = bf16c(accn[i][2]);
        TbufH[(quad * 4 + 3) * 1024 + e] = bf16c(accn[i][3]);
    }
    if (w == 0) {
        accden += __shfl_xor(accden, 16, 64);
        accden += __shfl_xor(accden, 32, 64);
        if (l < 16) den[(size_t)(c * BS + b) * H + l] = accden;
    }
    __syncthreads();
    // 16*1024 shorts = 2048 uint4; 4 iters x 512 threads
    uint4* numv = (uint4*)(num + ((size_t)(c * BS + b) * H) * E);
    const uint4* tb = (const uint4*)TbufH;
    #pragma unroll
    for (int k = 0; k < 4; k++)
        numv[k * 512 + tid] = tb[k * 512 + tid];
}

// ---- 4. combine + ctx: block per (h, 4 batches); num is bf16 ----
__global__ void k_pc(const unsigned short* __restrict__ num, const float* __restrict__ den,
                     const float* __restrict__ w_in, const float* __restrict__ b_in,
                     float* __restrict__ ctx) {
    int h = blockIdx.x, b0 = blockIdx.y * 4, t = threadIdx.x;
    __shared__ float p_l[4][1024];
    __shared__ float cred[4][64][4];
    __shared__ float inv_l[4];
    #pragma unroll
    for (int k = 0; k < 4; k++) {
        int idx4 = k * 256 + t;
        int bb = idx4 >> 8, e4 = (idx4 & 255) * 4;
        float4 a = make_float4(0.f, 0.f, 0.f, 0.f);
        #pragma unroll
        for (int cc = 0; cc < CATT; cc++) {
            uint2 v = *(const uint2*)(num + (((size_t)(cc * BS + b0 + bb) * H + h) * E) + e4);
            a.x += __uint_as_float(v.x << 16);
            a.y += __uint_as_float(v.x & 0xffff0000u);
            a.z += __uint_as_float(v.y << 16);
            a.w += __uint_as_float(v.y & 0xffff0000u);
        }
        *(float4*)&p_l[bb][e4] = a;
    }
    if (t < 4) {
        float ds = 0.f;
        for (int cc = 0; cc < CATT; cc++) ds += den[(size_t)(cc * BS + b0 + t) * H + h];
        inv_l[t] = 1.0f / ds;
    }
    __syncthreads();
    {
        int jj = t >> 2, part = t & 3;
        const float* wr = w_in + (size_t)(2 * E + h * HD + jj) * E + part * 256;
        float acc[4] = {0.f, 0.f, 0.f, 0.f};
        #pragma unroll 8
        for (int i = 0; i < 64; i++) {
            float4 wv = *(const float4*)(wr + i * 4);
            #pragma unroll
            for (int bb = 0; bb < 4; bb++)
                acc[bb] += dot4(wv, *(const float4*)&p_l[bb][part * 256 + i * 4]);
        }
        #pragma unroll
        for (int bb = 0; bb < 4; bb++) cred[bb][jj][part] = acc[bb];
    }
    __syncthreads();
    if (t < 64) {
        float bias = b_in[2 * E + h * HD + t];
        #pragma unroll
        for (int bb = 0; bb < 4; bb++) {
            float s = cred[bb][t][0] + cred[bb][t][1] + cred[bb][t][2] + cred[bb][t][3];
            ctx[(size_t)(b0 + bb) * E + h * HD + t] = inv_l[bb] * s + bias;
        }
    }
}

// ---- 5. out = origin_q + strength * (ctx @ Wout^T + bout), gated ----
__global__ void k_out(const float* __restrict__ model, const float* __restrict__ w_out,
                      const float* __restrict__ b_out, const float* __restrict__ ctx,
                      const int* __restrict__ mp, const int* __restrict__ empty,
                      const float* __restrict__ strength_p, float* __restrict__ out) {
    int w = threadIdx.x >> 6, l = threadIdx.x & 63;
    int j = blockIdx.x * 4 + w;
    int b0 = blockIdx.y * 8;
    const float* wr = w_out + (size_t)j * E;
    float4 wv[4];
    #pragma unroll
    for (int r = 0; r < 4; r++) wv[r] = *(const float4*)(wr + r * 256 + l * 4);
    float acc[8];
    #pragma unroll
    for (int bb = 0; bb < 8; bb++) {
        const float* src = ctx + (size_t)(b0 + bb) * E;
        float a = 0.f;
        #pragma unroll
        for (int r = 0; r < 4; r++) a += dot4(wv[r], *(const float4*)(src + r * 256 + l * 4));
        acc[bb] = a;
    }
    bfly8(acc);
    if (l < 8) {
        float myacc = acc[0];
        #pragma unroll
        for (int bb = 1; bb < 8; bb++) myacc = (l == bb) ? acc[bb] : myacc;
        int b = b0 + l;
        int m = mp[b];
        float orig = model[((size_t)(b * S + m)) * E + j];
        float bias = b_out[j];
        float st = strength_p[0];
        out[(size_t)b * E + j] = empty[b] ? orig : orig + st * (myacc + bias);
    }
}

extern "C" void kernel_launch(void* const* d_in, const int* in_sizes, int n_in,
                              void* d_out, int out_size, void* d_ws, size_t ws_size,
                              hipStream_t stream) {
    const float* model     = (const float*)d_in[0];
    const float* knowledge = (const float*)d_in[1];
    const float* w_in      = (const float*)d_in[2];
    const float* b_in      = (const float*)d_in[3];
    const float* w_out     = (const float*)d_in[4];
    const float* b_out     = (const float*)d_in[5];
    const float* strength  = (const float*)d_in[6];
    const int*   ids       = (const int*)d_in[7];
    const int*   empty     = (const int*)d_in[8];
    const int*   know_id   = (const int*)d_in[9];
    const int*   mask_id   = (const int*)d_in[10];
    float* out = (float*)d_out;

    float* ws  = (float*)d_ws;
    int*   mp  = (int*)d_ws;
    float* qin = ws + W_QIN;
    unsigned short* qkbf = (unsigned short*)(ws + W_QKBF);
    unsigned short* num  = (unsigned short*)(ws + W_NUM);
    float* den = ws + W_DEN;
    float* ctx = ws + W_CTX;

    k_prep<<<BS, 256, 0, stream>>>(model, knowledge, ids, mask_id, know_id, mp, qin);
    k_qgen<<<dim3(H, 16), 256, 0, stream>>>(qin, w_in, b_in, qkbf);
    k_attn<<<dim3(CATT, BS), 512, 0, stream>>>(model, knowledge, ids, know_id, qkbf, num, den);
    k_pc<<<dim3(H, 16), 256, 0, stream>>>(num, den, w_in, b_in, ctx);
    k_out<<<dim3(256, 8), 256, 0, stream>>>(model, w_out, b_out, ctx, mp, empty, strength, out);
}